// Round 9
// baseline (1099.975 us; speedup 1.0000x reference)
//
#include <hip/hip_runtime.h>
#include <hip/hip_bf16.h>
#include <math.h>

#define NTOK 16384
#define HDIM 1024
#define DSZ 32
#define DGZ 32
#define FMZ 64
#define NEXP 4
#define FFZ 2048

typedef __attribute__((ext_vector_type(4))) float f32x4;
typedef __attribute__((ext_vector_type(8))) short bf16x8;

__device__ __forceinline__ unsigned short f2bf(float f){
    union { float f; unsigned int u; } v; v.f = f;
    unsigned int r = (v.u + 0x7FFFu + ((v.u >> 16) & 1u)) >> 16;
    return (unsigned short)r;
}
__device__ __forceinline__ float gelu_f(float x){
    return 0.5f * x * (1.0f + erff(x * 0.70710678118654752440f));
}
__device__ __forceinline__ void gld_lds16(const void* g, void* s){
    __builtin_amdgcn_global_load_lds((const __attribute__((address_space(1))) unsigned int*)g,
                                     (__attribute__((address_space(3))) unsigned int*)s, 16, 0, 0);
}

// ---------------- kernel 1: per-token LN stats only ----------------
__global__ __launch_bounds__(256) void k_stats(const float* __restrict__ h,
        float* __restrict__ mu_g, float* __restrict__ rs_g){
    int tid = threadIdx.x;
    int wv = tid >> 6, l = tid & 63;
    int tok = blockIdx.x * 4 + wv;
    const float4* hp = (const float4*)(h + (size_t)tok * HDIM);
    float s = 0.f, s2 = 0.f;
    #pragma unroll
    for (int p = 0; p < 4; ++p){
        float4 v = hp[p * 64 + l];
        s  += v.x + v.y + v.z + v.w;
        s2 += v.x*v.x + v.y*v.y + v.z*v.z + v.w*v.w;
    }
    #pragma unroll
    for (int off = 32; off >= 1; off >>= 1){
        s  += __shfl_xor(s,  off, 64);
        s2 += __shfl_xor(s2, off, 64);
    }
    if (l == 0){
        float mu = s * (1.0f / HDIM);
        float var = s2 * (1.0f / HDIM) - mu * mu;
        var = fmaxf(var, 0.f);
        mu_g[tok] = mu;
        rs_g[tok] = 1.0f / sqrtf(var + 1e-5f);
    }
}

// ---------------- kernel 2: transpose + fp32->bf16 (weights, per expert) ----------------
__global__ __launch_bounds__(256) void k_transpose_bf(const float* __restrict__ in,
        unsigned short* __restrict__ out, int R, int C){
    __shared__ float tile[32][33];
    size_t mat = (size_t)blockIdx.z * R * C;
    int bx = blockIdx.x * 32;   // col base
    int by = blockIdx.y * 32;   // row base
    int x = threadIdx.x, y = threadIdx.y;
    const float* ip = in + mat;
    unsigned short* op = out + mat;
    #pragma unroll
    for (int i = 0; i < 32; i += 8)
        tile[y + i][x] = ip[(size_t)(by + y + i) * C + (bx + x)];
    __syncthreads();
    #pragma unroll
    for (int i = 0; i < 32; i += 8)
        op[(size_t)(bx + y + i) * R + (by + x)] = f2bf(tile[x][y + i]);
}

// ---------------- kernel 3: fused fp32 routing (unchanged, verified) ----------------
__global__ __launch_bounds__(256) void k_route(
    const float* __restrict__ h, const float* __restrict__ tok_emb,
    const float* __restrict__ ln_g, const float* __restrict__ ln_b,
    const float* __restrict__ Wg, const float* __restrict__ bg,
    const float* __restrict__ Wf, const float* __restrict__ bfv,
    const float* __restrict__ Wr, const float* __restrict__ br,
    const float* __restrict__ mu_g, const float* __restrict__ rs_g,
    float* __restrict__ tprob, int* __restrict__ list, int* __restrict__ cnt,
    float* __restrict__ imp_part)
{
    __shared__ __align__(16) char smem[62208];
    float* lgs  = (float*)(smem);                      // [1024]
    float* lbs  = (float*)(smem + 4096);               // [1024]
    float (*hsT)[64]  = (float(*)[64])(smem + 8192);   // [64 k][64 tok]
    float (*wgs)[32]  = (float(*)[32])(smem + 24576);  // [64 k][32 c]
    float (*gacc)[32] = (float(*)[32])(smem + 32768);  // [64 tok][32 c]
    float* mus = (float*)(smem + 40960);               // [64]
    float* rss = (float*)(smem + 41216);               // [64]
    float (*wrs)[4]     = (float(*)[4])(smem + 41472); // [64][4]
    float (*logit_s)[5] = (float(*)[5])(smem + 42496);
    float (*prob_s)[5]  = (float(*)[5])(smem + 43776);
    int* lcnt  = (int*)(smem + 45056);
    int* lbase = (int*)(smem + 45072);
    float (*agT)[64] = (float(*)[64])(smem);           // [64 j][64 tok]
    float (*wfs)[64] = (float(*)[64])(smem + 16384);   // [64 k][64 f]
    float (*uT)[64]  = (float(*)[64])(smem + 45824);   // [64 f][64 tok]

    int tid = threadIdx.x;
    int t0 = blockIdx.x * 64;

    ((float4*)lgs)[tid] = ((const float4*)ln_g)[tid];
    ((float4*)lbs)[tid] = ((const float4*)ln_b)[tid];
    if (tid < 64){ mus[tid] = mu_g[t0 + tid]; rss[tid] = rs_g[t0 + tid]; }
    if (tid < 64) ((float4*)wrs)[tid] = ((const float4*)Wr)[tid];
    if (tid < 4) lcnt[tid] = 0;
    __syncthreads();

    int l = tid & 63, w = tid >> 6;
    int tg = l & 7, cg = l >> 3, q = w;
    float g_[8][4];
    #pragma unroll
    for (int i=0;i<8;++i){ g_[i][0]=0.f; g_[i][1]=0.f; g_[i][2]=0.f; g_[i][3]=0.f; }
    int tokrow = tid >> 2;
    float m_ = mus[tokrow], r_ = rss[tokrow];
    const float* hrow = h + (size_t)(t0 + tokrow) * HDIM;

    for (int k0 = 0; k0 < HDIM; k0 += 64){
        #pragma unroll
        for (int p = 0; p < 4; ++p){
            int f4 = (tid & 3) + 4 * p;
            float4 v = ((const float4*)(hrow + k0))[f4];
            int c = f4 * 4;
            hsT[c+0][tokrow] = (v.x - m_) * r_ * lgs[k0+c+0] + lbs[k0+c+0];
            hsT[c+1][tokrow] = (v.y - m_) * r_ * lgs[k0+c+1] + lbs[k0+c+1];
            hsT[c+2][tokrow] = (v.z - m_) * r_ * lgs[k0+c+2] + lbs[k0+c+2];
            hsT[c+3][tokrow] = (v.w - m_) * r_ * lgs[k0+c+3] + lbs[k0+c+3];
        }
        {
            int wgrow = tid >> 2;
            #pragma unroll
            for (int p = 0; p < 2; ++p){
                int f4 = (tid & 3) + 4 * p;
                ((float4*)wgs[wgrow])[f4] = ((const float4*)(Wg + (size_t)(k0 + wgrow) * DGZ))[f4];
            }
        }
        __syncthreads();
        #pragma unroll
        for (int kk16 = 0; kk16 < 16; ++kk16){
            int kk = q * 16 + kk16;
            float4 a0 = ((float4*)hsT[kk])[tg*2];
            float4 a1 = ((float4*)hsT[kk])[tg*2+1];
            float4 wv = ((float4*)wgs[kk])[cg];
            float av[8] = {a0.x,a0.y,a0.z,a0.w,a1.x,a1.y,a1.z,a1.w};
            float wj[4] = {wv.x,wv.y,wv.z,wv.w};
            #pragma unroll
            for (int i=0;i<8;++i){
                g_[i][0] += av[i]*wj[0]; g_[i][1] += av[i]*wj[1];
                g_[i][2] += av[i]*wj[2]; g_[i][3] += av[i]*wj[3];
            }
        }
        __syncthreads();
    }
    for (int qq = 0; qq < 4; ++qq){
        if (w == qq){
            #pragma unroll
            for (int i=0;i<8;++i){
                int tok = tg*8+i;
                #pragma unroll
                for (int j=0;j<4;++j){
                    int c = cg*4+j;
                    if (qq == 0) gacc[tok][c] = g_[i][j];
                    else gacc[tok][c] += g_[i][j];
                }
            }
        }
        __syncthreads();
    }
    {
        int tokr = tid >> 2;
        #pragma unroll
        for (int p = 0; p < 2; ++p){
            int f4 = (tid & 3) + 4*p;
            float4 v = ((const float4*)(tok_emb + (size_t)(t0 + tokr) * DSZ))[f4];
            int j = f4 * 4;
            agT[j+0][tokr] = v.x; agT[j+1][tokr] = v.y;
            agT[j+2][tokr] = v.z; agT[j+3][tokr] = v.w;
        }
        int c = tid & 31, tok8 = (tid >> 5) * 8;
        float bgc = bg[c];
        #pragma unroll
        for (int i=0;i<8;++i){
            int tok = tok8 + i;
            agT[32 + c][tok] = gelu_f(gacc[tok][c] + bgc);
        }
        int row = tid >> 2;
        #pragma unroll
        for (int p = 0; p < 4; ++p){
            int f4 = (tid & 3) + 4*p;
            ((float4*)wfs[row])[f4] = ((const float4*)(Wf + (size_t)row * FMZ))[f4];
        }
    }
    __syncthreads();
    {
        int tok = tid & 63, fq = tid >> 6;
        float u_[16];
        #pragma unroll
        for (int i=0;i<16;++i) u_[i]=0.f;
        for (int j = 0; j < 64; ++j){
            float a = agT[j][tok];
            float wv[16];
            *(float4*)&wv[0]  = ((float4*)wfs[j])[fq*4+0];
            *(float4*)&wv[4]  = ((float4*)wfs[j])[fq*4+1];
            *(float4*)&wv[8]  = ((float4*)wfs[j])[fq*4+2];
            *(float4*)&wv[12] = ((float4*)wfs[j])[fq*4+3];
            #pragma unroll
            for (int i=0;i<16;++i) u_[i] += a * wv[i];
        }
        #pragma unroll
        for (int i=0;i<16;++i){
            int f = fq*16+i;
            uT[f][tok] = gelu_f(u_[i] + bfv[f]);
        }
    }
    __syncthreads();
    {
        int tok = tid & 63, e = tid >> 6;
        float lt = 0.f;
        #pragma unroll 8
        for (int f = 0; f < 64; ++f) lt += uT[f][tok] * wrs[f][e];
        logit_s[tok][e] = lt + br[e];
    }
    __syncthreads();
    int my_e = 0, my_pos = 0;
    if (tid < 64){
        int tok = tid;
        float l0 = logit_s[tok][0], l1 = logit_s[tok][1];
        float l2 = logit_s[tok][2], l3 = logit_s[tok][3];
        float mx = fmaxf(fmaxf(l0,l1), fmaxf(l2,l3));
        float p0 = expf(l0-mx), p1 = expf(l1-mx), p2 = expf(l2-mx), p3 = expf(l3-mx);
        float inv = 1.0f / (p0+p1+p2+p3);
        int be = 0; float bp = p0;
        if (p1 > bp){ bp = p1; be = 1; }
        if (p2 > bp){ bp = p2; be = 2; }
        if (p3 > bp){ bp = p3; be = 3; }
        tprob[t0 + tok] = bp * inv;
        prob_s[tok][0] = p0*inv; prob_s[tok][1] = p1*inv;
        prob_s[tok][2] = p2*inv; prob_s[tok][3] = p3*inv;
        my_e = be;
        my_pos = atomicAdd(&lcnt[be], 1);
    }
    __syncthreads();
    if (tid < 4) lbase[tid] = atomicAdd(&cnt[tid], lcnt[tid]);
    __syncthreads();
    if (tid < 64) list[my_e * NTOK + lbase[my_e] + my_pos] = t0 + tid;
    if (tid < 4){
        float s = 0.f;
        for (int t = 0; t < 64; ++t) s += prob_s[t][tid];
        imp_part[blockIdx.x * 4 + tid] = s;
    }
}

// ---------------- kernel 3b: pack h rows into routing order (fp32 -> bf16) ----------------
__global__ __launch_bounds__(256) void k_pack(const float* __restrict__ h,
        const int* __restrict__ list, const int* __restrict__ cnt,
        unsigned short* __restrict__ Ap){
    int wv = threadIdx.x >> 6, l = threadIdx.x & 63;
    int p = blockIdx.x * 4 + wv;
    int b1 = cnt[0], b2 = b1 + cnt[1], b3 = b2 + cnt[2];
    int e, g;
    if (p < b1){ e = 0; g = p; }
    else if (p < b2){ e = 1; g = p - b1; }
    else if (p < b3){ e = 2; g = p - b2; }
    else { e = 3; g = p - b3; }
    int tok = list[e * NTOK + g];
    const float4* src = (const float4*)(h + (size_t)tok * HDIM);
    ushort4* dst = (ushort4*)(Ap + (size_t)p * HDIM);
    #pragma unroll
    for (int i = 0; i < 4; ++i){
        float4 v = src[l + 64 * i];
        ushort4 o; o.x = f2bf(v.x); o.y = f2bf(v.y); o.z = f2bf(v.z); o.w = f2bf(v.w);
        dst[l + 64 * i] = o;
    }
}

// ---------------- grouped GEMM v7: r2 structure + packed A + XCD swizzle + 5 blocks/CU ----------------
// 256 thr = 4 waves (2M x 2N), 128x128 tile, BK=64, SINGLE-buffer LDS 32 KiB,
// plain __syncthreads() (compiler-scheduled waitcnts, m97 discipline).
// __launch_bounds__(256,5): VGPR cap 102 (r2 measured 96) -> 5 blocks/CU co-resident
// (5 x 32KB = 160KB LDS exactly; 20 waves/CU). TLP hides the per-K-step barrier drain (m114).
// Swizzle (VERIFIED 0 conflicts in r2/r4): LDS[row][cp] = G[row][cp ^ (row&7)];
//   write: source chunk (l&7)^(l>>3) (row&7 == l>>3); read: byte ^ (l&7)<<4 (frag row&7 == l&7).
// XCD chunked swizzle (VERIFIED FETCH 142->68MB in r7): 4-consecutive logical tiles per XCD.
template<int KTD, int NT, bool PH1>
__global__ __launch_bounds__(256, 5) void k_gemm(
    const unsigned short* __restrict__ Abase,
    const unsigned short* __restrict__ Bbase,
    const int* __restrict__ list, const int* __restrict__ cnt_g,
    const float* __restrict__ bias,
    unsigned short* __restrict__ A1out,
    const float* __restrict__ hres,
    const float* __restrict__ tprob,
    float* __restrict__ outp)
{
    __shared__ __align__(16) unsigned short As[128 * 64];
    __shared__ __align__(16) unsigned short Bs[128 * 64];
    constexpr int GX = NT / 128;               // 16 (PH1) or 8 (PH2)
    int e = blockIdx.z;
    int cnt = cnt_g[e];
    // XCD chunked swizzle: f -> g, XCD xk gets 4-consecutive logical tiles per 32-block span
    int f = blockIdx.y * GX + blockIdx.x;
    int jj = f >> 3, xk = f & 7;
    int g = (jj >> 2) * 32 + xk * 4 + (jj & 3);
    int m0 = (g / GX) * 128;
    int n0 = (g % GX) * 128;
    if (m0 >= cnt) return;
    int pb = 0;
    #pragma unroll
    for (int i = 0; i < 3; ++i) if (i < e) pb += cnt_g[i];
    int tid = threadIdx.x, w = tid >> 6, l = tid & 63;
    int wr = w >> 1, wc = w & 1;

    // staging: instr i covers rows 8w+(l>>3)+32i; source chunk pre-swizzled
    int csw = ((l & 7) ^ (l >> 3)) * 8;
    const unsigned short* aptr[4];
    const unsigned short* bptr[4];
    #pragma unroll
    for (int i = 0; i < 4; ++i){
        int row = 8 * w + (l >> 3) + 32 * i;
        int ga = m0 + row; if (ga > cnt - 1) ga = cnt - 1;
        aptr[i] = Abase + (size_t)(pb + ga) * KTD + csw;
        bptr[i] = Bbase + ((size_t)e * NT + (n0 + row)) * KTD + csw;
    }
    f32x4 acc[4][4] = {};
    int rsw = (l & 7) << 4;
    for (int k0 = 0; k0 < KTD; k0 += 64){
        #pragma unroll
        for (int i = 0; i < 4; ++i)
            gld_lds16(aptr[i] + k0, (char*)As + w * 1024 + i * 4096);
        #pragma unroll
        for (int i = 0; i < 4; ++i)
            gld_lds16(bptr[i] + k0, (char*)Bs + w * 1024 + i * 4096);
        __syncthreads();
        #pragma unroll
        for (int kk = 0; kk < 2; ++kk){
            bf16x8 a[4], b[4];
            #pragma unroll
            for (int m = 0; m < 4; ++m)
                a[m] = *(const bf16x8*)((const char*)As + (wr*64 + m*16 + (l&15))*128 + ((kk*64 + (l>>4)*16) ^ rsw));
            #pragma unroll
            for (int n = 0; n < 4; ++n)
                b[n] = *(const bf16x8*)((const char*)Bs + (wc*64 + n*16 + (l&15))*128 + ((kk*64 + (l>>4)*16) ^ rsw));
            #pragma unroll
            for (int m = 0; m < 4; ++m)
                #pragma unroll
                for (int n = 0; n < 4; ++n)
                    acc[m][n] = __builtin_amdgcn_mfma_f32_16x16x32_bf16(a[m], b[n], acc[m][n], 0, 0, 0);
        }
        __syncthreads();
    }

    // epilogue: C/D layout col = lane&15 (+16*n), row = (lane>>4)*4 + reg (+16*m)
    float bs[4];
    #pragma unroll
    for (int n = 0; n < 4; ++n)
        bs[n] = bias[e * NT + n0 + wc * 64 + n * 16 + (l & 15)];
    #pragma unroll
    for (int m = 0; m < 4; ++m){
        #pragma unroll
        for (int r = 0; r < 4; ++r){
            int row = wr * 64 + m * 16 + (l >> 4) * 4 + r;
            int gg = m0 + row;
            if (gg < cnt){
                if (PH1){
                    #pragma unroll
                    for (int n = 0; n < 4; ++n){
                        int col = n0 + wc * 64 + n * 16 + (l & 15);
                        float v = acc[m][n][r] + bs[n];
                        A1out[(size_t)(pb + gg) * FFZ + col] = f2bf(gelu_f(v));
                    }
                } else {
                    int tok = list[e * NTOK + gg];
                    float sc = 0.5f * tprob[tok];
                    #pragma unroll
                    for (int n = 0; n < 4; ++n){
                        int col = n0 + wc * 64 + n * 16 + (l & 15);
                        float v = acc[m][n][r] + bs[n];
                        size_t o = (size_t)tok * HDIM + col;
                        outp[o] = hres[o] + sc * v;
                    }
                }
            }
        }
    }
}

// ---------------- final: lb_loss ----------------
__global__ void k_final(const float* __restrict__ imp_part, const int* __restrict__ cnt,
                        float* __restrict__ outp){
    __shared__ float imp_s[4];
    int tid = threadIdx.x;
    if (tid < 4){
        float s = 0.f;
        for (int b = 0; b < 256; ++b) s += imp_part[b*4 + tid];
        imp_s[tid] = s;
    }
    __syncthreads();
    if (tid == 0){
        float lb = 0.f;
        #pragma unroll
        for (int e = 0; e < 4; ++e) lb += imp_s[e] * (float)cnt[e];
        outp[(size_t)NTOK * HDIM] = (float)NEXP * lb / ((float)NTOK * (float)NTOK + 1e-8f);
    }
}

extern "C" void kernel_launch(void* const* d_in, const int* in_sizes, int n_in,
                              void* d_out, int out_size, void* d_ws, size_t ws_size,
                              hipStream_t stream){
    const float* h       = (const float*)d_in[0];
    const float* tok_emb = (const float*)d_in[1];
    const float* ln_g = (const float*)d_in[3];
    const float* ln_b = (const float*)d_in[4];
    const float* Wg   = (const float*)d_in[5];
    const float* bg   = (const float*)d_in[6];
    const float* Wf   = (const float*)d_in[7];
    const float* bfv  = (const float*)d_in[8];
    const float* Wr   = (const float*)d_in[9];
    const float* br   = (const float*)d_in[10];
    const float* W1   = (const float*)d_in[11];
    const float* b1   = (const float*)d_in[12];
    const float* W2   = (const float*)d_in[13];
    const float* b2   = (const float*)d_in[14];
    float* outp = (float*)d_out;
    char* ws = (char*)d_ws;

    unsigned short* Ap   = (unsigned short*)(ws);               // 33554432 B  packed h rows (bf16)
    unsigned short* W1T  = (unsigned short*)(ws + 33554432);    // 16777216 B  [E][FFZ][HDIM]
    unsigned short* W2T  = (unsigned short*)(ws + 50331648);    // 16777216 B  [E][HDIM][FFZ]
    unsigned short* A1   = (unsigned short*)(ws + 67108864);    // 67108864 B  packed [NTOK][FFZ]
    float* mu_g  = (float*)(ws + 134217728);
    float* rs_g  = (float*)(ws + 134283264);
    float* tprob = (float*)(ws + 134348800);
    int*   list  = (int*)(ws + 134414336);                      // [E][NTOK]
    int*   cnt   = (int*)(ws + 134676480);                      // [E]
    float* imp   = (float*)(ws + 134676736);                    // [256][E]

    hipMemsetAsync(cnt, 0, NEXP * sizeof(int), stream);
    k_stats<<<NTOK/4, 256, 0, stream>>>(h, mu_g, rs_g);
    k_transpose_bf<<<dim3(FFZ/32, HDIM/32, NEXP), dim3(32,8), 0, stream>>>(W1, W1T, HDIM, FFZ);
    k_transpose_bf<<<dim3(HDIM/32, FFZ/32, NEXP), dim3(32,8), 0, stream>>>(W2, W2T, FFZ, HDIM);
    k_route<<<NTOK/64, 256, 0, stream>>>(h, tok_emb, ln_g, ln_b, Wg, bg, Wf, bfv, Wr, br,
                                         mu_g, rs_g, tprob, list, cnt, imp);
    k_pack<<<NTOK/4, 256, 0, stream>>>(h, list, cnt, Ap);
    k_gemm<HDIM, FFZ, true><<<dim3(FFZ/128, NTOK/128, NEXP), 256, 0, stream>>>(
        Ap, W1T, list, cnt, b1, A1, nullptr, nullptr, nullptr);
    k_gemm<FFZ, HDIM, false><<<dim3(HDIM/128, NTOK/128, NEXP), 256, 0, stream>>>(
        A1, W2T, list, cnt, b2, nullptr, h, tprob, outp);
    k_final<<<1, 64, 0, stream>>>(imp, cnt, outp);
}

// Round 10
// 394.428 us; speedup vs baseline: 2.7888x; 2.7888x over previous
//
#include <hip/hip_runtime.h>
#include <hip/hip_bf16.h>
#include <math.h>

#define NTOK 16384
#define HDIM 1024
#define DSZ 32
#define DGZ 32
#define FMZ 64
#define NEXP 4
#define FFZ 2048

typedef __attribute__((ext_vector_type(4))) float f32x4;
typedef __attribute__((ext_vector_type(8))) short bf16x8;

__device__ __forceinline__ unsigned short f2bf(float f){
    union { float f; unsigned int u; } v; v.f = f;
    unsigned int r = (v.u + 0x7FFFu + ((v.u >> 16) & 1u)) >> 16;
    return (unsigned short)r;
}
__device__ __forceinline__ float gelu_f(float x){
    return 0.5f * x * (1.0f + erff(x * 0.70710678118654752440f));
}
__device__ __forceinline__ void gld_lds16(const void* g, void* s){
    __builtin_amdgcn_global_load_lds((const __attribute__((address_space(1))) unsigned int*)g,
                                     (__attribute__((address_space(3))) unsigned int*)s, 16, 0, 0);
}

// ---------------- kernel 1: per-token LN stats only ----------------
__global__ __launch_bounds__(256) void k_stats(const float* __restrict__ h,
        float* __restrict__ mu_g, float* __restrict__ rs_g){
    int tid = threadIdx.x;
    int wv = tid >> 6, l = tid & 63;
    int tok = blockIdx.x * 4 + wv;
    const float4* hp = (const float4*)(h + (size_t)tok * HDIM);
    float s = 0.f, s2 = 0.f;
    #pragma unroll
    for (int p = 0; p < 4; ++p){
        float4 v = hp[p * 64 + l];
        s  += v.x + v.y + v.z + v.w;
        s2 += v.x*v.x + v.y*v.y + v.z*v.z + v.w*v.w;
    }
    #pragma unroll
    for (int off = 32; off >= 1; off >>= 1){
        s  += __shfl_xor(s,  off, 64);
        s2 += __shfl_xor(s2, off, 64);
    }
    if (l == 0){
        float mu = s * (1.0f / HDIM);
        float var = s2 * (1.0f / HDIM) - mu * mu;
        var = fmaxf(var, 0.f);
        mu_g[tok] = mu;
        rs_g[tok] = 1.0f / sqrtf(var + 1e-5f);
    }
}

// ---------------- kernel 2: transpose + fp32->bf16 (weights, per expert) ----------------
__global__ __launch_bounds__(256) void k_transpose_bf(const float* __restrict__ in,
        unsigned short* __restrict__ out, int R, int C){
    __shared__ float tile[32][33];
    size_t mat = (size_t)blockIdx.z * R * C;
    int bx = blockIdx.x * 32;   // col base
    int by = blockIdx.y * 32;   // row base
    int x = threadIdx.x, y = threadIdx.y;
    const float* ip = in + mat;
    unsigned short* op = out + mat;
    #pragma unroll
    for (int i = 0; i < 32; i += 8)
        tile[y + i][x] = ip[(size_t)(by + y + i) * C + (bx + x)];
    __syncthreads();
    #pragma unroll
    for (int i = 0; i < 32; i += 8)
        op[(size_t)(bx + y + i) * R + (by + x)] = f2bf(tile[x][y + i]);
}

// ---------------- kernel 3: fused fp32 routing (unchanged, verified) ----------------
__global__ __launch_bounds__(256) void k_route(
    const float* __restrict__ h, const float* __restrict__ tok_emb,
    const float* __restrict__ ln_g, const float* __restrict__ ln_b,
    const float* __restrict__ Wg, const float* __restrict__ bg,
    const float* __restrict__ Wf, const float* __restrict__ bfv,
    const float* __restrict__ Wr, const float* __restrict__ br,
    const float* __restrict__ mu_g, const float* __restrict__ rs_g,
    float* __restrict__ tprob, int* __restrict__ list, int* __restrict__ cnt,
    float* __restrict__ imp_part)
{
    __shared__ __align__(16) char smem[62208];
    float* lgs  = (float*)(smem);                      // [1024]
    float* lbs  = (float*)(smem + 4096);               // [1024]
    float (*hsT)[64]  = (float(*)[64])(smem + 8192);   // [64 k][64 tok]
    float (*wgs)[32]  = (float(*)[32])(smem + 24576);  // [64 k][32 c]
    float (*gacc)[32] = (float(*)[32])(smem + 32768);  // [64 tok][32 c]
    float* mus = (float*)(smem + 40960);               // [64]
    float* rss = (float*)(smem + 41216);               // [64]
    float (*wrs)[4]     = (float(*)[4])(smem + 41472); // [64][4]
    float (*logit_s)[5] = (float(*)[5])(smem + 42496);
    float (*prob_s)[5]  = (float(*)[5])(smem + 43776);
    int* lcnt  = (int*)(smem + 45056);
    int* lbase = (int*)(smem + 45072);
    float (*agT)[64] = (float(*)[64])(smem);           // [64 j][64 tok]
    float (*wfs)[64] = (float(*)[64])(smem + 16384);   // [64 k][64 f]
    float (*uT)[64]  = (float(*)[64])(smem + 45824);   // [64 f][64 tok]

    int tid = threadIdx.x;
    int t0 = blockIdx.x * 64;

    ((float4*)lgs)[tid] = ((const float4*)ln_g)[tid];
    ((float4*)lbs)[tid] = ((const float4*)ln_b)[tid];
    if (tid < 64){ mus[tid] = mu_g[t0 + tid]; rss[tid] = rs_g[t0 + tid]; }
    if (tid < 64) ((float4*)wrs)[tid] = ((const float4*)Wr)[tid];
    if (tid < 4) lcnt[tid] = 0;
    __syncthreads();

    int l = tid & 63, w = tid >> 6;
    int tg = l & 7, cg = l >> 3, q = w;
    float g_[8][4];
    #pragma unroll
    for (int i=0;i<8;++i){ g_[i][0]=0.f; g_[i][1]=0.f; g_[i][2]=0.f; g_[i][3]=0.f; }
    int tokrow = tid >> 2;
    float m_ = mus[tokrow], r_ = rss[tokrow];
    const float* hrow = h + (size_t)(t0 + tokrow) * HDIM;

    for (int k0 = 0; k0 < HDIM; k0 += 64){
        #pragma unroll
        for (int p = 0; p < 4; ++p){
            int f4 = (tid & 3) + 4 * p;
            float4 v = ((const float4*)(hrow + k0))[f4];
            int c = f4 * 4;
            hsT[c+0][tokrow] = (v.x - m_) * r_ * lgs[k0+c+0] + lbs[k0+c+0];
            hsT[c+1][tokrow] = (v.y - m_) * r_ * lgs[k0+c+1] + lbs[k0+c+1];
            hsT[c+2][tokrow] = (v.z - m_) * r_ * lgs[k0+c+2] + lbs[k0+c+2];
            hsT[c+3][tokrow] = (v.w - m_) * r_ * lgs[k0+c+3] + lbs[k0+c+3];
        }
        {
            int wgrow = tid >> 2;
            #pragma unroll
            for (int p = 0; p < 2; ++p){
                int f4 = (tid & 3) + 4 * p;
                ((float4*)wgs[wgrow])[f4] = ((const float4*)(Wg + (size_t)(k0 + wgrow) * DGZ))[f4];
            }
        }
        __syncthreads();
        #pragma unroll
        for (int kk16 = 0; kk16 < 16; ++kk16){
            int kk = q * 16 + kk16;
            float4 a0 = ((float4*)hsT[kk])[tg*2];
            float4 a1 = ((float4*)hsT[kk])[tg*2+1];
            float4 wv = ((float4*)wgs[kk])[cg];
            float av[8] = {a0.x,a0.y,a0.z,a0.w,a1.x,a1.y,a1.z,a1.w};
            float wj[4] = {wv.x,wv.y,wv.z,wv.w};
            #pragma unroll
            for (int i=0;i<8;++i){
                g_[i][0] += av[i]*wj[0]; g_[i][1] += av[i]*wj[1];
                g_[i][2] += av[i]*wj[2]; g_[i][3] += av[i]*wj[3];
            }
        }
        __syncthreads();
    }
    for (int qq = 0; qq < 4; ++qq){
        if (w == qq){
            #pragma unroll
            for (int i=0;i<8;++i){
                int tok = tg*8+i;
                #pragma unroll
                for (int j=0;j<4;++j){
                    int c = cg*4+j;
                    if (qq == 0) gacc[tok][c] = g_[i][j];
                    else gacc[tok][c] += g_[i][j];
                }
            }
        }
        __syncthreads();
    }
    {
        int tokr = tid >> 2;
        #pragma unroll
        for (int p = 0; p < 2; ++p){
            int f4 = (tid & 3) + 4*p;
            float4 v = ((const float4*)(tok_emb + (size_t)(t0 + tokr) * DSZ))[f4];
            int j = f4 * 4;
            agT[j+0][tokr] = v.x; agT[j+1][tokr] = v.y;
            agT[j+2][tokr] = v.z; agT[j+3][tokr] = v.w;
        }
        int c = tid & 31, tok8 = (tid >> 5) * 8;
        float bgc = bg[c];
        #pragma unroll
        for (int i=0;i<8;++i){
            int tok = tok8 + i;
            agT[32 + c][tok] = gelu_f(gacc[tok][c] + bgc);
        }
        int row = tid >> 2;
        #pragma unroll
        for (int p = 0; p < 4; ++p){
            int f4 = (tid & 3) + 4*p;
            ((float4*)wfs[row])[f4] = ((const float4*)(Wf + (size_t)row * FMZ))[f4];
        }
    }
    __syncthreads();
    {
        int tok = tid & 63, fq = tid >> 6;
        float u_[16];
        #pragma unroll
        for (int i=0;i<16;++i) u_[i]=0.f;
        for (int j = 0; j < 64; ++j){
            float a = agT[j][tok];
            float wv[16];
            *(float4*)&wv[0]  = ((float4*)wfs[j])[fq*4+0];
            *(float4*)&wv[4]  = ((float4*)wfs[j])[fq*4+1];
            *(float4*)&wv[8]  = ((float4*)wfs[j])[fq*4+2];
            *(float4*)&wv[12] = ((float4*)wfs[j])[fq*4+3];
            #pragma unroll
            for (int i=0;i<16;++i) u_[i] += a * wv[i];
        }
        #pragma unroll
        for (int i=0;i<16;++i){
            int f = fq*16+i;
            uT[f][tok] = gelu_f(u_[i] + bfv[f]);
        }
    }
    __syncthreads();
    {
        int tok = tid & 63, e = tid >> 6;
        float lt = 0.f;
        #pragma unroll 8
        for (int f = 0; f < 64; ++f) lt += uT[f][tok] * wrs[f][e];
        logit_s[tok][e] = lt + br[e];
    }
    __syncthreads();
    int my_e = 0, my_pos = 0;
    if (tid < 64){
        int tok = tid;
        float l0 = logit_s[tok][0], l1 = logit_s[tok][1];
        float l2 = logit_s[tok][2], l3 = logit_s[tok][3];
        float mx = fmaxf(fmaxf(l0,l1), fmaxf(l2,l3));
        float p0 = expf(l0-mx), p1 = expf(l1-mx), p2 = expf(l2-mx), p3 = expf(l3-mx);
        float inv = 1.0f / (p0+p1+p2+p3);
        int be = 0; float bp = p0;
        if (p1 > bp){ bp = p1; be = 1; }
        if (p2 > bp){ bp = p2; be = 2; }
        if (p3 > bp){ bp = p3; be = 3; }
        tprob[t0 + tok] = bp * inv;
        prob_s[tok][0] = p0*inv; prob_s[tok][1] = p1*inv;
        prob_s[tok][2] = p2*inv; prob_s[tok][3] = p3*inv;
        my_e = be;
        my_pos = atomicAdd(&lcnt[be], 1);
    }
    __syncthreads();
    if (tid < 4) lbase[tid] = atomicAdd(&cnt[tid], lcnt[tid]);
    __syncthreads();
    if (tid < 64) list[my_e * NTOK + lbase[my_e] + my_pos] = t0 + tid;
    if (tid < 4){
        float s = 0.f;
        for (int t = 0; t < 64; ++t) s += prob_s[t][tid];
        imp_part[blockIdx.x * 4 + tid] = s;
    }
}

// ---------------- kernel 3b: pack h rows into routing order (fp32 -> bf16) ----------------
__global__ __launch_bounds__(256) void k_pack(const float* __restrict__ h,
        const int* __restrict__ list, const int* __restrict__ cnt,
        unsigned short* __restrict__ Ap){
    int wv = threadIdx.x >> 6, l = threadIdx.x & 63;
    int p = blockIdx.x * 4 + wv;
    int b1 = cnt[0], b2 = b1 + cnt[1], b3 = b2 + cnt[2];
    int e, g;
    if (p < b1){ e = 0; g = p; }
    else if (p < b2){ e = 1; g = p - b1; }
    else if (p < b3){ e = 2; g = p - b2; }
    else { e = 3; g = p - b3; }
    int tok = list[e * NTOK + g];
    const float4* src = (const float4*)(h + (size_t)tok * HDIM);
    ushort4* dst = (ushort4*)(Ap + (size_t)p * HDIM);
    #pragma unroll
    for (int i = 0; i < 4; ++i){
        float4 v = src[l + 64 * i];
        ushort4 o; o.x = f2bf(v.x); o.y = f2bf(v.y); o.z = f2bf(v.z); o.w = f2bf(v.w);
        dst[l + 64 * i] = o;
    }
}

// ---------------- grouped GEMM v8: r6 8-phase 256² core + FLAT ACTIVE-TILE DISPATCH ----------------
// 1-D grid over ACTIVE tiles only: mt = flat/GX walks a prefix over ceil(cnt_e/256);
// live blocks are contiguous in dispatch order (no dead-block dilution of CU residency).
// m204 bijective XCD swizzle on the flat index: each XCD gets a contiguous logical
// range; consecutive logical tiles (same m-tile, n-fastest) share the A panel in L2.
// GEMM core (phases, swizzle, staging, vmcnt(8) discipline) is r6's verified kernel.
template<int KTD, int NT, bool PH1, int NWG>
__global__ __launch_bounds__(512, 2) void k_gemm256(
    const unsigned short* __restrict__ Abase,
    const unsigned short* __restrict__ Bbase,
    const int* __restrict__ list, const int* __restrict__ cnt_g,
    const float* __restrict__ bias,
    unsigned short* __restrict__ A1out,
    const float* __restrict__ hres,
    const float* __restrict__ tprob,
    float* __restrict__ outp)
{
    constexpr int NKT = KTD / 64;
    constexpr int NKTm1 = NKT - 1;
    constexpr int GX = NT / 256;               // 8 (PH1) or 4 (PH2)
    __shared__ __align__(16) char lds[131072];

    // m204 bijective XCD swizzle over the launched 1-D grid
    int p = blockIdx.x;
    int xcd = p & 7, pos = p >> 3;
    constexpr int Q = NWG >> 3, R = NWG & 7;
    int base = xcd < R ? xcd * (Q + 1) : R * (Q + 1) + (xcd - R) * Q;
    int fl = base + pos;
    int mt = fl / GX, nn = fl % GX;

    // active-tile prefix mapping: mt -> (expert e, local m-tile)
    int c0 = cnt_g[0], c1 = cnt_g[1], c2 = cnt_g[2], c3 = cnt_g[3];
    int nt0 = (c0 + 255) >> 8, nt1 = (c1 + 255) >> 8, nt2 = (c2 + 255) >> 8;
    int nt3 = (c3 + 255) >> 8;
    if (mt >= nt0 + nt1 + nt2 + nt3) return;
    int e = 0, pb = 0, mtl = mt, cnt = c0;
    if (mtl >= nt0){ mtl -= nt0; pb += c0; e = 1; cnt = c1;
        if (mtl >= nt1){ mtl -= nt1; pb += c1; e = 2; cnt = c2;
            if (mtl >= nt2){ mtl -= nt2; pb += c2; e = 3; cnt = c3; } } }
    int m0 = mtl * 256;
    int n0 = nn * 256;

    int tid = threadIdx.x, w = tid >> 6, l = tid & 63;
    int wr = w >> 2, wc = w & 3;

    // staging mapping: thread -> (row = tid>>2 [+128 on 2nd load], src chunk jsrc)
    int srow = tid >> 2;
    int jsrc = (tid & 3) ^ ((tid >> 3) & 3);
    int g0 = m0 + srow;       if (g0 > cnt-1) g0 = cnt-1;
    int g1 = m0 + 128 + srow; if (g1 > cnt-1) g1 = cnt-1;
    const unsigned short* Asrc0 = Abase + (size_t)(pb + g0) * KTD + jsrc * 8;
    const unsigned short* Asrc1 = Abase + (size_t)(pb + g1) * KTD + jsrc * 8;
    const unsigned short* Bsrc0 = Bbase + ((size_t)e * NT + n0 + srow) * KTD + jsrc * 8;
    const unsigned short* Bsrc1 = Bsrc0 + (size_t)128 * KTD;

    // fragment read offsets (swizzled: chunk = (l>>4) ^ (((l&15)>>1)&3), 2-way banks)
    int lane_off = (l & 15) * 64 + (((l >> 4) ^ (((l & 15) >> 1) & 3)) * 16);
    char* abase = lds + wr * 8192 + lane_off;            // + DOF + KCB + mh*4096 + m*1024
    char* bbase = lds + 65536 + wc * 4096 + lane_off;    // + DOF + KCB + n*1024

#define STAGE_A(KIDX, KC, DOF) do { \
    int kq_ = (KIDX); if (kq_ > NKTm1) kq_ = NKTm1; \
    size_t so_ = (size_t)kq_ * 64 + (KC) * 32; \
    gld_lds16(Asrc0 + so_, lds + (DOF) + (KC) * 16384 + tid * 16); \
    gld_lds16(Asrc1 + so_, lds + (DOF) + (KC) * 16384 + 8192 + tid * 16); } while(0)
#define STAGE_B(KIDX, KC, DOF) do { \
    int kq_ = (KIDX); if (kq_ > NKTm1) kq_ = NKTm1; \
    size_t so_ = (size_t)kq_ * 64 + (KC) * 32; \
    gld_lds16(Bsrc0 + so_, lds + 65536 + (DOF) + (KC) * 16384 + tid * 16); \
    gld_lds16(Bsrc1 + so_, lds + 65536 + (DOF) + (KC) * 16384 + 8192 + tid * 16); } while(0)
#define AFRAG(DOF, KCB, MH, M) (*(const bf16x8*)(abase + (DOF) + (KCB) + (MH) * 4096 + (M) * 1024))
#define BFRAG(DOF, KCB, N)     (*(const bf16x8*)(bbase + (DOF) + (KCB) + (N) * 1024))
#define MM16(MB, A0, A1, A2, A3) do { \
    acc[(MB)+0][0] = __builtin_amdgcn_mfma_f32_16x16x32_bf16(A0, b0, acc[(MB)+0][0], 0,0,0); \
    acc[(MB)+1][0] = __builtin_amdgcn_mfma_f32_16x16x32_bf16(A1, b0, acc[(MB)+1][0], 0,0,0); \
    acc[(MB)+2][0] = __builtin_amdgcn_mfma_f32_16x16x32_bf16(A2, b0, acc[(MB)+2][0], 0,0,0); \
    acc[(MB)+3][0] = __builtin_amdgcn_mfma_f32_16x16x32_bf16(A3, b0, acc[(MB)+3][0], 0,0,0); \
    acc[(MB)+0][1] = __builtin_amdgcn_mfma_f32_16x16x32_bf16(A0, b1, acc[(MB)+0][1], 0,0,0); \
    acc[(MB)+1][1] = __builtin_amdgcn_mfma_f32_16x16x32_bf16(A1, b1, acc[(MB)+1][1], 0,0,0); \
    acc[(MB)+2][1] = __builtin_amdgcn_mfma_f32_16x16x32_bf16(A2, b1, acc[(MB)+2][1], 0,0,0); \
    acc[(MB)+3][1] = __builtin_amdgcn_mfma_f32_16x16x32_bf16(A3, b1, acc[(MB)+3][1], 0,0,0); \
    acc[(MB)+0][2] = __builtin_amdgcn_mfma_f32_16x16x32_bf16(A0, b2, acc[(MB)+0][2], 0,0,0); \
    acc[(MB)+1][2] = __builtin_amdgcn_mfma_f32_16x16x32_bf16(A1, b2, acc[(MB)+1][2], 0,0,0); \
    acc[(MB)+2][2] = __builtin_amdgcn_mfma_f32_16x16x32_bf16(A2, b2, acc[(MB)+2][2], 0,0,0); \
    acc[(MB)+3][2] = __builtin_amdgcn_mfma_f32_16x16x32_bf16(A3, b2, acc[(MB)+3][2], 0,0,0); \
    acc[(MB)+0][3] = __builtin_amdgcn_mfma_f32_16x16x32_bf16(A0, b3, acc[(MB)+0][3], 0,0,0); \
    acc[(MB)+1][3] = __builtin_amdgcn_mfma_f32_16x16x32_bf16(A1, b3, acc[(MB)+1][3], 0,0,0); \
    acc[(MB)+2][3] = __builtin_amdgcn_mfma_f32_16x16x32_bf16(A2, b3, acc[(MB)+2][3], 0,0,0); \
    acc[(MB)+3][3] = __builtin_amdgcn_mfma_f32_16x16x32_bf16(A3, b3, acc[(MB)+3][3], 0,0,0); } while(0)

// PH_AB: loads A mh0 + B fragments of (DOF,KCB), stages one A half-tile, MFMA quadrant 0
#define PH_AB(DOF, KCB, SK, SKC, SDOF) do { \
    bf16x8 a0 = AFRAG(DOF,KCB,0,0), a1 = AFRAG(DOF,KCB,0,1), a2 = AFRAG(DOF,KCB,0,2), a3 = AFRAG(DOF,KCB,0,3); \
    b0 = BFRAG(DOF,KCB,0); b1 = BFRAG(DOF,KCB,1); b2 = BFRAG(DOF,KCB,2); b3 = BFRAG(DOF,KCB,3); \
    STAGE_A(SK, SKC, SDOF); \
    __builtin_amdgcn_s_barrier(); \
    __builtin_amdgcn_s_setprio(1); \
    MM16(0, a0, a1, a2, a3); \
    __builtin_amdgcn_s_setprio(0); \
    asm volatile("s_waitcnt lgkmcnt(0)" ::: "memory"); \
    __builtin_amdgcn_s_barrier(); } while(0)
// PH_A: loads A mh1 fragments (reuses b0..b3), stages one B half-tile, MFMA quadrant 1,
//       counted vmcnt(8) fence (4 half-tiles stay in flight)
#define PH_A(DOF, KCB, SK, SKC, SDOF) do { \
    bf16x8 a0 = AFRAG(DOF,KCB,1,0), a1 = AFRAG(DOF,KCB,1,1), a2 = AFRAG(DOF,KCB,1,2), a3 = AFRAG(DOF,KCB,1,3); \
    STAGE_B(SK, SKC, SDOF); \
    __builtin_amdgcn_s_barrier(); \
    __builtin_amdgcn_s_setprio(1); \
    MM16(4, a0, a1, a2, a3); \
    __builtin_amdgcn_s_setprio(0); \
    asm volatile("s_waitcnt vmcnt(8) lgkmcnt(0)" ::: "memory"); \
    __builtin_amdgcn_s_barrier(); } while(0)

    f32x4 acc[8][4] = {};
    bf16x8 b0, b1, b2, b3;

    // prologue: stage (0,kc0,D0),(0,kc1,D0),(1,kc0,D1); retire (0,kc0) -> 8 in flight
    STAGE_A(0, 0, 0);     STAGE_B(0, 0, 0);
    STAGE_A(0, 1, 0);     STAGE_B(0, 1, 0);
    STAGE_A(1, 0, 32768); STAGE_B(1, 0, 32768);
    asm volatile("s_waitcnt vmcnt(8)" ::: "memory");
    __builtin_amdgcn_s_barrier();

    #pragma unroll 1
    for (int kt = 0; kt < NKT; kt += 2){
        // K-tile kt (buffer 0)
        PH_AB(0,     0,     kt+1, 1, 32768);
        PH_A (0,     0,     kt+1, 1, 32768);
        PH_AB(0,     16384, kt+2, 0, 0);
        PH_A (0,     16384, kt+2, 0, 0);
        // K-tile kt+1 (buffer 32768)
        PH_AB(32768, 0,     kt+2, 1, 0);
        PH_A (32768, 0,     kt+2, 1, 0);
        PH_AB(32768, 16384, kt+3, 0, 32768);
        PH_A (32768, 16384, kt+3, 0, 32768);
    }

    // epilogue: C/D layout col = lane&15 (+16*n), row = (lane>>4)*4 + reg (+16*M)
    float bs[4];
    #pragma unroll
    for (int n = 0; n < 4; ++n)
        bs[n] = bias[e * NT + n0 + wc * 64 + n * 16 + (l & 15)];
    #pragma unroll
    for (int M = 0; M < 8; ++M){
        #pragma unroll
        for (int r = 0; r < 4; ++r){
            int row = wr * 128 + M * 16 + (l >> 4) * 4 + r;
            int g = m0 + row;
            if (g < cnt){
                if (PH1){
                    #pragma unroll
                    for (int n = 0; n < 4; ++n){
                        int col = n0 + wc * 64 + n * 16 + (l & 15);
                        float v = acc[M][n][r] + bs[n];
                        A1out[(size_t)(pb + g) * FFZ + col] = f2bf(gelu_f(v));
                    }
                } else {
                    int tok = list[e * NTOK + g];
                    float sc = 0.5f * tprob[tok];
                    #pragma unroll
                    for (int n = 0; n < 4; ++n){
                        int col = n0 + wc * 64 + n * 16 + (l & 15);
                        float v = acc[M][n][r] + bs[n];
                        size_t o = (size_t)tok * HDIM + col;
                        outp[o] = hres[o] + sc * v;
                    }
                }
            }
        }
    }
#undef STAGE_A
#undef STAGE_B
#undef AFRAG
#undef BFRAG
#undef MM16
#undef PH_AB
#undef PH_A
}

// ---------------- final: lb_loss ----------------
__global__ void k_final(const float* __restrict__ imp_part, const int* __restrict__ cnt,
                        float* __restrict__ outp){
    __shared__ float imp_s[4];
    int tid = threadIdx.x;
    if (tid < 4){
        float s = 0.f;
        for (int b = 0; b < 256; ++b) s += imp_part[b*4 + tid];
        imp_s[tid] = s;
    }
    __syncthreads();
    if (tid == 0){
        float lb = 0.f;
        #pragma unroll
        for (int e = 0; e < 4; ++e) lb += imp_s[e] * (float)cnt[e];
        outp[(size_t)NTOK * HDIM] = (float)NEXP * lb / ((float)NTOK * (float)NTOK + 1e-8f);
    }
}

extern "C" void kernel_launch(void* const* d_in, const int* in_sizes, int n_in,
                              void* d_out, int out_size, void* d_ws, size_t ws_size,
                              hipStream_t stream){
    const float* h       = (const float*)d_in[0];
    const float* tok_emb = (const float*)d_in[1];
    const float* ln_g = (const float*)d_in[3];
    const float* ln_b = (const float*)d_in[4];
    const float* Wg   = (const float*)d_in[5];
    const float* bg   = (const float*)d_in[6];
    const float* Wf   = (const float*)d_in[7];
    const float* bfv  = (const float*)d_in[8];
    const float* Wr   = (const float*)d_in[9];
    const float* br   = (const float*)d_in[10];
    const float* W1   = (const float*)d_in[11];
    const float* b1   = (const float*)d_in[12];
    const float* W2   = (const float*)d_in[13];
    const float* b2   = (const float*)d_in[14];
    float* outp = (float*)d_out;
    char* ws = (char*)d_ws;

    unsigned short* Ap   = (unsigned short*)(ws);               // 33554432 B  packed h rows (bf16)
    unsigned short* W1T  = (unsigned short*)(ws + 33554432);    // 16777216 B  [E][FFZ][HDIM]
    unsigned short* W2T  = (unsigned short*)(ws + 50331648);    // 16777216 B  [E][HDIM][FFZ]
    unsigned short* A1   = (unsigned short*)(ws + 67108864);    // 67108864 B  packed [NTOK][FFZ]
    float* mu_g  = (float*)(ws + 134217728);
    float* rs_g  = (float*)(ws + 134283264);
    float* tprob = (float*)(ws + 134348800);
    int*   list  = (int*)(ws + 134414336);                      // [E][NTOK]
    int*   cnt   = (int*)(ws + 134676480);                      // [E]
    float* imp   = (float*)(ws + 134676736);                    // [256][E]

    // flat 1-D grids over active tiles (worst case: one expert owns all tokens -> 64+3 m-tiles)
    constexpr int NWG1 = (NTOK/256 + 3) * (FFZ/256);   // 536
    constexpr int NWG2 = (NTOK/256 + 3) * (HDIM/256);  // 268

    hipMemsetAsync(cnt, 0, NEXP * sizeof(int), stream);
    k_stats<<<NTOK/4, 256, 0, stream>>>(h, mu_g, rs_g);
    k_transpose_bf<<<dim3(FFZ/32, HDIM/32, NEXP), dim3(32,8), 0, stream>>>(W1, W1T, HDIM, FFZ);
    k_transpose_bf<<<dim3(HDIM/32, FFZ/32, NEXP), dim3(32,8), 0, stream>>>(W2, W2T, FFZ, HDIM);
    k_route<<<NTOK/64, 256, 0, stream>>>(h, tok_emb, ln_g, ln_b, Wg, bg, Wf, bfv, Wr, br,
                                         mu_g, rs_g, tprob, list, cnt, imp);
    k_pack<<<NTOK/4, 256, 0, stream>>>(h, list, cnt, Ap);
    k_gemm256<HDIM, FFZ, true, NWG1><<<NWG1, 512, 0, stream>>>(
        Ap, W1T, list, cnt, b1, A1, nullptr, nullptr, nullptr);
    k_gemm256<FFZ, HDIM, false, NWG2><<<NWG2, 512, 0, stream>>>(
        A1, W2T, list, cnt, b2, nullptr, h, tprob, outp);
    k_final<<<1, 64, 0, stream>>>(imp, cnt, outp);
}

// Round 11
// 366.097 us; speedup vs baseline: 3.0046x; 1.0774x over previous
//
#include <hip/hip_runtime.h>
#include <hip/hip_bf16.h>
#include <math.h>

#define NTOK 16384
#define HDIM 1024
#define DSZ 32
#define DGZ 32
#define FMZ 64
#define NEXP 4
#define FFZ 2048

typedef __attribute__((ext_vector_type(4))) float f32x4;
typedef __attribute__((ext_vector_type(8))) short bf16x8;

__device__ __forceinline__ unsigned short f2bf(float f){
    union { float f; unsigned int u; } v; v.f = f;
    unsigned int r = (v.u + 0x7FFFu + ((v.u >> 16) & 1u)) >> 16;
    return (unsigned short)r;
}
__device__ __forceinline__ float gelu_f(float x){
    return 0.5f * x * (1.0f + erff(x * 0.70710678118654752440f));
}
__device__ __forceinline__ void gld_lds16(const void* g, void* s){
    __builtin_amdgcn_global_load_lds((const __attribute__((address_space(1))) unsigned int*)g,
                                     (__attribute__((address_space(3))) unsigned int*)s, 16, 0, 0);
}

// ---------------- kernel 1: per-token LN stats only ----------------
__global__ __launch_bounds__(256) void k_stats(const float* __restrict__ h,
        float* __restrict__ mu_g, float* __restrict__ rs_g){
    int tid = threadIdx.x;
    int wv = tid >> 6, l = tid & 63;
    int tok = blockIdx.x * 4 + wv;
    const float4* hp = (const float4*)(h + (size_t)tok * HDIM);
    float s = 0.f, s2 = 0.f;
    #pragma unroll
    for (int p = 0; p < 4; ++p){
        float4 v = hp[p * 64 + l];
        s  += v.x + v.y + v.z + v.w;
        s2 += v.x*v.x + v.y*v.y + v.z*v.z + v.w*v.w;
    }
    #pragma unroll
    for (int off = 32; off >= 1; off >>= 1){
        s  += __shfl_xor(s,  off, 64);
        s2 += __shfl_xor(s2, off, 64);
    }
    if (l == 0){
        float mu = s * (1.0f / HDIM);
        float var = s2 * (1.0f / HDIM) - mu * mu;
        var = fmaxf(var, 0.f);
        mu_g[tok] = mu;
        rs_g[tok] = 1.0f / sqrtf(var + 1e-5f);
    }
}

// ---------------- kernel 2: transpose + fp32->bf16 (weights, per expert) ----------------
__global__ __launch_bounds__(256) void k_transpose_bf(const float* __restrict__ in,
        unsigned short* __restrict__ out, int R, int C){
    __shared__ float tile[32][33];
    size_t mat = (size_t)blockIdx.z * R * C;
    int bx = blockIdx.x * 32;   // col base
    int by = blockIdx.y * 32;   // row base
    int x = threadIdx.x, y = threadIdx.y;
    const float* ip = in + mat;
    unsigned short* op = out + mat;
    #pragma unroll
    for (int i = 0; i < 32; i += 8)
        tile[y + i][x] = ip[(size_t)(by + y + i) * C + (bx + x)];
    __syncthreads();
    #pragma unroll
    for (int i = 0; i < 32; i += 8)
        op[(size_t)(bx + y + i) * R + (by + x)] = f2bf(tile[x][y + i]);
}

// ---------------- kernel 3: fused fp32 routing (unchanged, verified) ----------------
__global__ __launch_bounds__(256) void k_route(
    const float* __restrict__ h, const float* __restrict__ tok_emb,
    const float* __restrict__ ln_g, const float* __restrict__ ln_b,
    const float* __restrict__ Wg, const float* __restrict__ bg,
    const float* __restrict__ Wf, const float* __restrict__ bfv,
    const float* __restrict__ Wr, const float* __restrict__ br,
    const float* __restrict__ mu_g, const float* __restrict__ rs_g,
    float* __restrict__ tprob, int* __restrict__ list, int* __restrict__ cnt,
    float* __restrict__ imp_part)
{
    __shared__ __align__(16) char smem[62208];
    float* lgs  = (float*)(smem);                      // [1024]
    float* lbs  = (float*)(smem + 4096);               // [1024]
    float (*hsT)[64]  = (float(*)[64])(smem + 8192);   // [64 k][64 tok]
    float (*wgs)[32]  = (float(*)[32])(smem + 24576);  // [64 k][32 c]
    float (*gacc)[32] = (float(*)[32])(smem + 32768);  // [64 tok][32 c]
    float* mus = (float*)(smem + 40960);               // [64]
    float* rss = (float*)(smem + 41216);               // [64]
    float (*wrs)[4]     = (float(*)[4])(smem + 41472); // [64][4]
    float (*logit_s)[5] = (float(*)[5])(smem + 42496);
    float (*prob_s)[5]  = (float(*)[5])(smem + 43776);
    int* lcnt  = (int*)(smem + 45056);
    int* lbase = (int*)(smem + 45072);
    float (*agT)[64] = (float(*)[64])(smem);           // [64 j][64 tok]
    float (*wfs)[64] = (float(*)[64])(smem + 16384);   // [64 k][64 f]
    float (*uT)[64]  = (float(*)[64])(smem + 45824);   // [64 f][64 tok]

    int tid = threadIdx.x;
    int t0 = blockIdx.x * 64;

    ((float4*)lgs)[tid] = ((const float4*)ln_g)[tid];
    ((float4*)lbs)[tid] = ((const float4*)ln_b)[tid];
    if (tid < 64){ mus[tid] = mu_g[t0 + tid]; rss[tid] = rs_g[t0 + tid]; }
    if (tid < 64) ((float4*)wrs)[tid] = ((const float4*)Wr)[tid];
    if (tid < 4) lcnt[tid] = 0;
    __syncthreads();

    int l = tid & 63, w = tid >> 6;
    int tg = l & 7, cg = l >> 3, q = w;
    float g_[8][4];
    #pragma unroll
    for (int i=0;i<8;++i){ g_[i][0]=0.f; g_[i][1]=0.f; g_[i][2]=0.f; g_[i][3]=0.f; }
    int tokrow = tid >> 2;
    float m_ = mus[tokrow], r_ = rss[tokrow];
    const float* hrow = h + (size_t)(t0 + tokrow) * HDIM;

    for (int k0 = 0; k0 < HDIM; k0 += 64){
        #pragma unroll
        for (int p = 0; p < 4; ++p){
            int f4 = (tid & 3) + 4 * p;
            float4 v = ((const float4*)(hrow + k0))[f4];
            int c = f4 * 4;
            hsT[c+0][tokrow] = (v.x - m_) * r_ * lgs[k0+c+0] + lbs[k0+c+0];
            hsT[c+1][tokrow] = (v.y - m_) * r_ * lgs[k0+c+1] + lbs[k0+c+1];
            hsT[c+2][tokrow] = (v.z - m_) * r_ * lgs[k0+c+2] + lbs[k0+c+2];
            hsT[c+3][tokrow] = (v.w - m_) * r_ * lgs[k0+c+3] + lbs[k0+c+3];
        }
        {
            int wgrow = tid >> 2;
            #pragma unroll
            for (int p = 0; p < 2; ++p){
                int f4 = (tid & 3) + 4 * p;
                ((float4*)wgs[wgrow])[f4] = ((const float4*)(Wg + (size_t)(k0 + wgrow) * DGZ))[f4];
            }
        }
        __syncthreads();
        #pragma unroll
        for (int kk16 = 0; kk16 < 16; ++kk16){
            int kk = q * 16 + kk16;
            float4 a0 = ((float4*)hsT[kk])[tg*2];
            float4 a1 = ((float4*)hsT[kk])[tg*2+1];
            float4 wv = ((float4*)wgs[kk])[cg];
            float av[8] = {a0.x,a0.y,a0.z,a0.w,a1.x,a1.y,a1.z,a1.w};
            float wj[4] = {wv.x,wv.y,wv.z,wv.w};
            #pragma unroll
            for (int i=0;i<8;++i){
                g_[i][0] += av[i]*wj[0]; g_[i][1] += av[i]*wj[1];
                g_[i][2] += av[i]*wj[2]; g_[i][3] += av[i]*wj[3];
            }
        }
        __syncthreads();
    }
    for (int qq = 0; qq < 4; ++qq){
        if (w == qq){
            #pragma unroll
            for (int i=0;i<8;++i){
                int tok = tg*8+i;
                #pragma unroll
                for (int j=0;j<4;++j){
                    int c = cg*4+j;
                    if (qq == 0) gacc[tok][c] = g_[i][j];
                    else gacc[tok][c] += g_[i][j];
                }
            }
        }
        __syncthreads();
    }
    {
        int tokr = tid >> 2;
        #pragma unroll
        for (int p = 0; p < 2; ++p){
            int f4 = (tid & 3) + 4*p;
            float4 v = ((const float4*)(tok_emb + (size_t)(t0 + tokr) * DSZ))[f4];
            int j = f4 * 4;
            agT[j+0][tokr] = v.x; agT[j+1][tokr] = v.y;
            agT[j+2][tokr] = v.z; agT[j+3][tokr] = v.w;
        }
        int c = tid & 31, tok8 = (tid >> 5) * 8;
        float bgc = bg[c];
        #pragma unroll
        for (int i=0;i<8;++i){
            int tok = tok8 + i;
            agT[32 + c][tok] = gelu_f(gacc[tok][c] + bgc);
        }
        int row = tid >> 2;
        #pragma unroll
        for (int p = 0; p < 4; ++p){
            int f4 = (tid & 3) + 4*p;
            ((float4*)wfs[row])[f4] = ((const float4*)(Wf + (size_t)row * FMZ))[f4];
        }
    }
    __syncthreads();
    {
        int tok = tid & 63, fq = tid >> 6;
        float u_[16];
        #pragma unroll
        for (int i=0;i<16;++i) u_[i]=0.f;
        for (int j = 0; j < 64; ++j){
            float a = agT[j][tok];
            float wv[16];
            *(float4*)&wv[0]  = ((float4*)wfs[j])[fq*4+0];
            *(float4*)&wv[4]  = ((float4*)wfs[j])[fq*4+1];
            *(float4*)&wv[8]  = ((float4*)wfs[j])[fq*4+2];
            *(float4*)&wv[12] = ((float4*)wfs[j])[fq*4+3];
            #pragma unroll
            for (int i=0;i<16;++i) u_[i] += a * wv[i];
        }
        #pragma unroll
        for (int i=0;i<16;++i){
            int f = fq*16+i;
            uT[f][tok] = gelu_f(u_[i] + bfv[f]);
        }
    }
    __syncthreads();
    {
        int tok = tid & 63, e = tid >> 6;
        float lt = 0.f;
        #pragma unroll 8
        for (int f = 0; f < 64; ++f) lt += uT[f][tok] * wrs[f][e];
        logit_s[tok][e] = lt + br[e];
    }
    __syncthreads();
    int my_e = 0, my_pos = 0;
    if (tid < 64){
        int tok = tid;
        float l0 = logit_s[tok][0], l1 = logit_s[tok][1];
        float l2 = logit_s[tok][2], l3 = logit_s[tok][3];
        float mx = fmaxf(fmaxf(l0,l1), fmaxf(l2,l3));
        float p0 = expf(l0-mx), p1 = expf(l1-mx), p2 = expf(l2-mx), p3 = expf(l3-mx);
        float inv = 1.0f / (p0+p1+p2+p3);
        int be = 0; float bp = p0;
        if (p1 > bp){ bp = p1; be = 1; }
        if (p2 > bp){ bp = p2; be = 2; }
        if (p3 > bp){ bp = p3; be = 3; }
        tprob[t0 + tok] = bp * inv;
        prob_s[tok][0] = p0*inv; prob_s[tok][1] = p1*inv;
        prob_s[tok][2] = p2*inv; prob_s[tok][3] = p3*inv;
        my_e = be;
        my_pos = atomicAdd(&lcnt[be], 1);
    }
    __syncthreads();
    if (tid < 4) lbase[tid] = atomicAdd(&cnt[tid], lcnt[tid]);
    __syncthreads();
    if (tid < 64) list[my_e * NTOK + lbase[my_e] + my_pos] = t0 + tid;
    if (tid < 4){
        float s = 0.f;
        for (int t = 0; t < 64; ++t) s += prob_s[t][tid];
        imp_part[blockIdx.x * 4 + tid] = s;
    }
}

// ---------------- kernel 3b: pack h rows into routing order (fp32 -> bf16) ----------------
__global__ __launch_bounds__(256) void k_pack(const float* __restrict__ h,
        const int* __restrict__ list, const int* __restrict__ cnt,
        unsigned short* __restrict__ Ap){
    int wv = threadIdx.x >> 6, l = threadIdx.x & 63;
    int p = blockIdx.x * 4 + wv;
    int b1 = cnt[0], b2 = b1 + cnt[1], b3 = b2 + cnt[2];
    int e, g;
    if (p < b1){ e = 0; g = p; }
    else if (p < b2){ e = 1; g = p - b1; }
    else if (p < b3){ e = 2; g = p - b2; }
    else { e = 3; g = p - b3; }
    int tok = list[e * NTOK + g];
    const float4* src = (const float4*)(h + (size_t)tok * HDIM);
    ushort4* dst = (ushort4*)(Ap + (size_t)p * HDIM);
    #pragma unroll
    for (int i = 0; i < 4; ++i){
        float4 v = src[l + 64 * i];
        ushort4 o; o.x = f2bf(v.x); o.y = f2bf(v.y); o.z = f2bf(v.z); o.w = f2bf(v.w);
        dst[l + 64 * i] = o;
    }
}

// ---------------- grouped GEMM v9: r2 core (128x128, 32KB LDS) + flat dispatch = 4-5 blocks/CU ----------------
// 256 thr = 4 waves (2M x 2N), BK=64, SINGLE-buffer 32 KiB LDS, plain __syncthreads(),
// compiler-scheduled waitcnts (m97 discipline). TLP does the latency hiding: flat live-tile
// grid gives 8 (PH1) / 4 (PH2) blocks per CU, 4-5 co-resident (LDS 32KBx5 = 160KB;
// VGPR ~96-104 -> 4-5 waves/SIMD). NO __launch_bounds__ min-wave arg (r9 spill lesson).
// Swizzle (verified 0-conflict in r2/r4): LDS[row][cp] = G[row][cp ^ (row&7)], source
// pre-swizzled (gld_lds dest linear, rule #21), read XORs byte with (l&7)<<4.
// m204 bijective XCD swizzle on the flat index; n fastest -> A-panel L2 reuse per XCD.
template<int KTD, int NT, bool PH1, int NWG>
__global__ __launch_bounds__(256) void k_gemm(
    const unsigned short* __restrict__ Abase,
    const unsigned short* __restrict__ Bbase,
    const int* __restrict__ list, const int* __restrict__ cnt_g,
    const float* __restrict__ bias,
    unsigned short* __restrict__ A1out,
    const float* __restrict__ hres,
    const float* __restrict__ tprob,
    float* __restrict__ outp)
{
    __shared__ __align__(16) unsigned short As[128 * 64];
    __shared__ __align__(16) unsigned short Bs[128 * 64];
    constexpr int GX = NT / 128;               // 16 (PH1) or 8 (PH2)

    // m204 bijective XCD swizzle over the flat 1-D grid
    int p = blockIdx.x;
    int xcd = p & 7, pos = p >> 3;
    constexpr int Q = NWG >> 3, R = NWG & 7;
    int base = xcd < R ? xcd * (Q + 1) : R * (Q + 1) + (xcd - R) * Q;
    int fl = base + pos;
    int mt = fl / GX, nn = fl % GX;

    // active-tile prefix mapping: mt -> (expert e, packed base pb, local m-tile)
    int c0 = cnt_g[0], c1 = cnt_g[1], c2 = cnt_g[2], c3 = cnt_g[3];
    int nt0 = (c0 + 127) >> 7, nt1 = (c1 + 127) >> 7, nt2 = (c2 + 127) >> 7;
    int nt3 = (c3 + 127) >> 7;
    if (mt >= nt0 + nt1 + nt2 + nt3) return;
    int e = 0, pb = 0, mtl = mt, cnt = c0;
    if (mtl >= nt0){ mtl -= nt0; pb += c0; e = 1; cnt = c1;
        if (mtl >= nt1){ mtl -= nt1; pb += c1; e = 2; cnt = c2;
            if (mtl >= nt2){ mtl -= nt2; pb += c2; e = 3; cnt = c3; } } }
    int m0 = mtl * 128;
    int n0 = nn * 128;

    int tid = threadIdx.x, w = tid >> 6, l = tid & 63;
    int wr = w >> 1, wc = w & 1;

    // staging: instr i covers rows 8w+(l>>3)+32i; source chunk pre-swizzled
    int csw = ((l & 7) ^ (l >> 3)) * 8;
    const unsigned short* aptr[4];
    const unsigned short* bptr[4];
    #pragma unroll
    for (int i = 0; i < 4; ++i){
        int row = 8 * w + (l >> 3) + 32 * i;
        int ga = m0 + row; if (ga > cnt - 1) ga = cnt - 1;
        aptr[i] = Abase + (size_t)(pb + ga) * KTD + csw;
        bptr[i] = Bbase + ((size_t)e * NT + (n0 + row)) * KTD + csw;
    }
    f32x4 acc[4][4] = {};
    int rsw = (l & 7) << 4;
    for (int k0 = 0; k0 < KTD; k0 += 64){
        #pragma unroll
        for (int i = 0; i < 4; ++i)
            gld_lds16(aptr[i] + k0, (char*)As + w * 1024 + i * 4096);
        #pragma unroll
        for (int i = 0; i < 4; ++i)
            gld_lds16(bptr[i] + k0, (char*)Bs + w * 1024 + i * 4096);
        __syncthreads();
        #pragma unroll
        for (int kk = 0; kk < 2; ++kk){
            bf16x8 a[4], b[4];
            #pragma unroll
            for (int m = 0; m < 4; ++m)
                a[m] = *(const bf16x8*)((const char*)As + (wr*64 + m*16 + (l&15))*128 + ((kk*64 + (l>>4)*16) ^ rsw));
            #pragma unroll
            for (int n = 0; n < 4; ++n)
                b[n] = *(const bf16x8*)((const char*)Bs + (wc*64 + n*16 + (l&15))*128 + ((kk*64 + (l>>4)*16) ^ rsw));
            #pragma unroll
            for (int m = 0; m < 4; ++m)
                #pragma unroll
                for (int n = 0; n < 4; ++n)
                    acc[m][n] = __builtin_amdgcn_mfma_f32_16x16x32_bf16(a[m], b[n], acc[m][n], 0, 0, 0);
        }
        __syncthreads();
    }

    // epilogue: C/D layout col = lane&15 (+16*n), row = (lane>>4)*4 + reg (+16*m)
    float bs[4];
    #pragma unroll
    for (int n = 0; n < 4; ++n)
        bs[n] = bias[e * NT + n0 + wc * 64 + n * 16 + (l & 15)];
    #pragma unroll
    for (int m = 0; m < 4; ++m){
        #pragma unroll
        for (int r = 0; r < 4; ++r){
            int row = wr * 64 + m * 16 + (l >> 4) * 4 + r;
            int gg = m0 + row;
            if (gg < cnt){
                if (PH1){
                    #pragma unroll
                    for (int n = 0; n < 4; ++n){
                        int col = n0 + wc * 64 + n * 16 + (l & 15);
                        float v = acc[m][n][r] + bs[n];
                        A1out[(size_t)(pb + gg) * FFZ + col] = f2bf(gelu_f(v));
                    }
                } else {
                    int tok = list[e * NTOK + gg];
                    float sc = 0.5f * tprob[tok];
                    #pragma unroll
                    for (int n = 0; n < 4; ++n){
                        int col = n0 + wc * 64 + n * 16 + (l & 15);
                        float v = acc[m][n][r] + bs[n];
                        size_t o = (size_t)tok * HDIM + col;
                        outp[o] = hres[o] + sc * v;
                    }
                }
            }
        }
    }
}

// ---------------- final: lb_loss ----------------
__global__ void k_final(const float* __restrict__ imp_part, const int* __restrict__ cnt,
                        float* __restrict__ outp){
    __shared__ float imp_s[4];
    int tid = threadIdx.x;
    if (tid < 4){
        float s = 0.f;
        for (int b = 0; b < 256; ++b) s += imp_part[b*4 + tid];
        imp_s[tid] = s;
    }
    __syncthreads();
    if (tid == 0){
        float lb = 0.f;
        #pragma unroll
        for (int e = 0; e < 4; ++e) lb += imp_s[e] * (float)cnt[e];
        outp[(size_t)NTOK * HDIM] = (float)NEXP * lb / ((float)NTOK * (float)NTOK + 1e-8f);
    }
}

extern "C" void kernel_launch(void* const* d_in, const int* in_sizes, int n_in,
                              void* d_out, int out_size, void* d_ws, size_t ws_size,
                              hipStream_t stream){
    const float* h       = (const float*)d_in[0];
    const float* tok_emb = (const float*)d_in[1];
    const float* ln_g = (const float*)d_in[3];
    const float* ln_b = (const float*)d_in[4];
    const float* Wg   = (const float*)d_in[5];
    const float* bg   = (const float*)d_in[6];
    const float* Wf   = (const float*)d_in[7];
    const float* bfv  = (const float*)d_in[8];
    const float* Wr   = (const float*)d_in[9];
    const float* br   = (const float*)d_in[10];
    const float* W1   = (const float*)d_in[11];
    const float* b1   = (const float*)d_in[12];
    const float* W2   = (const float*)d_in[13];
    const float* b2   = (const float*)d_in[14];
    float* outp = (float*)d_out;
    char* ws = (char*)d_ws;

    unsigned short* Ap   = (unsigned short*)(ws);               // 33554432 B  packed h rows (bf16)
    unsigned short* W1T  = (unsigned short*)(ws + 33554432);    // 16777216 B  [E][FFZ][HDIM]
    unsigned short* W2T  = (unsigned short*)(ws + 50331648);    // 16777216 B  [E][HDIM][FFZ]
    unsigned short* A1   = (unsigned short*)(ws + 67108864);    // 67108864 B  packed [NTOK][FFZ]
    float* mu_g  = (float*)(ws + 134217728);
    float* rs_g  = (float*)(ws + 134283264);
    float* tprob = (float*)(ws + 134348800);
    int*   list  = (int*)(ws + 134414336);                      // [E][NTOK]
    int*   cnt   = (int*)(ws + 134676480);                      // [E]
    float* imp   = (float*)(ws + 134676736);                    // [256][E]

    // flat 1-D grids over active 128x128 tiles
    // worst case m-tiles: sum ceil(cnt_e/128) <= NTOK/128 + 3 = 131
    constexpr int NWG1 = (NTOK/128 + 3) * (FFZ/128);   // 2096
    constexpr int NWG2 = (NTOK/128 + 3) * (HDIM/128);  // 1048

    hipMemsetAsync(cnt, 0, NEXP * sizeof(int), stream);
    k_stats<<<NTOK/4, 256, 0, stream>>>(h, mu_g, rs_g);
    k_transpose_bf<<<dim3(FFZ/32, HDIM/32, NEXP), dim3(32,8), 0, stream>>>(W1, W1T, HDIM, FFZ);
    k_transpose_bf<<<dim3(HDIM/32, FFZ/32, NEXP), dim3(32,8), 0, stream>>>(W2, W2T, FFZ, HDIM);
    k_route<<<NTOK/64, 256, 0, stream>>>(h, tok_emb, ln_g, ln_b, Wg, bg, Wf, bfv, Wr, br,
                                         mu_g, rs_g, tprob, list, cnt, imp);
    k_pack<<<NTOK/4, 256, 0, stream>>>(h, list, cnt, Ap);
    k_gemm<HDIM, FFZ, true, NWG1><<<NWG1, 256, 0, stream>>>(
        Ap, W1T, list, cnt, b1, A1, nullptr, nullptr, nullptr);
    k_gemm<FFZ, HDIM, false, NWG2><<<NWG2, 256, 0, stream>>>(
        A1, W2T, list, cnt, b2, nullptr, h, tprob, outp);
    k_final<<<1, 64, 0, stream>>>(imp, cnt, outp);
}